// Round 1
// baseline (7238.773 us; speedup 1.0000x reference)
//
#include <hip/hip_runtime.h>

typedef unsigned int uint32;

#define GBLK 256
#define BT 512
#define NSTEP 128

struct Params {
  const int* inputs;
  const float *h1_in, *h2_in, *embeds, *vatt;
  const float *pk, *enc, *Wq, *Wih1, *Whh1, *Wih2, *Whh2, *Wpre, *Wout;
  const float *bih1, *bhh1, *bih2, *bhh2, *bpre, *bout;
  float* out;
  float* ws;
  int* bar;
};

__device__ __forceinline__ float blo(uint32 u) { return __uint_as_float(u << 16); }
__device__ __forceinline__ float bhi(uint32 u) { return __uint_as_float(u & 0xffff0000u); }
__device__ __forceinline__ uint32 bfr(float f) {  // fp32 -> bf16 bits, RNE
  uint32 u = __float_as_uint(f);
  return (u + 0x7fffu + ((u >> 16) & 1u)) >> 16;
}

// Agent-scope (MALL-coherent, L2-bypassing) state access. Cross-block state
// flows ONLY through these, so barriers need no acquire -> no buffer_inv.
__device__ __forceinline__ float ald(const float* a) {
  return __hip_atomic_load(a, __ATOMIC_RELAXED, __HIP_MEMORY_SCOPE_AGENT);
}
__device__ __forceinline__ void ast(float* a, float v) {
  __hip_atomic_store(a, v, __ATOMIC_RELAXED, __HIP_MEMORY_SCOPE_AGENT);
}

__device__ __forceinline__ float wsum(float v) {
#pragma unroll
  for (int o = 32; o; o >>= 1) v += __shfl_xor(v, o, 64);
  return v;
}

// Load one 512-elem chunk (this lane's 8-elem slice) of fp32 W, pack into
// 4 registers of 2xbf16. Done ONCE at kernel start; weights then live in
// VGPRs for all 128 steps (231 KB/block << 512 KB/CU register file).
__device__ __forceinline__ void ldchunk(const float* W, size_t base, int lane, uint32* r) {
  const float* wf = W + base + lane * 8;
  float4 a = *(const float4*)wf;
  float4 c = *(const float4*)(wf + 4);
  r[0] = bfr(a.x) | (bfr(a.y) << 16);
  r[1] = bfr(a.z) | (bfr(a.w) << 16);
  r[2] = bfr(c.x) | (bfr(c.y) << 16);
  r[3] = bfr(c.z) | (bfr(c.w) << 16);
}

// dot of register-resident bf16 chunk against LDS x chunk (this lane's slice)
__device__ __forceinline__ float dotchunk(const uint32* r, const float* xc, int lane) {
  const float* x = xc + lane * 8;
  float4 x0 = *(const float4*)x, x1 = *(const float4*)(x + 4);
  return blo(r[0]) * x0.x + bhi(r[0]) * x0.y + blo(r[1]) * x0.z + bhi(r[1]) * x0.w +
         blo(r[2]) * x1.x + bhi(r[2]) * x1.y + blo(r[3]) * x1.z + bhi(r[3]) * x1.w;
}

// Barrier v3: 16 groups x 16 blocks; two-level arrival AND two-level release.
__device__ __forceinline__ void gbar(int* bar, int k) {
  __syncthreads();
  if (threadIdx.x == 0) {
    const int grp = blockIdx.x >> 4;
    int* gcnt = bar + grp * 32;         // group arrival counter (128B apart)
    int* grel = bar + 512 + grp * 32;   // group release word
    int* rcnt = bar + 1024;             // root arrival counter
    int* rrel = bar + 1056;             // root release word (separate line)
    int v = __hip_atomic_fetch_add(gcnt, 1, __ATOMIC_RELEASE, __HIP_MEMORY_SCOPE_AGENT);
    if (v == k * 16 - 1) {  // last block of this group
      int r = __hip_atomic_fetch_add(rcnt, 1, __ATOMIC_RELEASE, __HIP_MEMORY_SCOPE_AGENT);
      if (r == k * 16 - 1)
        __hip_atomic_store(rrel, k, __ATOMIC_RELAXED, __HIP_MEMORY_SCOPE_AGENT);
      while (__hip_atomic_load(rrel, __ATOMIC_RELAXED, __HIP_MEMORY_SCOPE_AGENT) < k)
        __builtin_amdgcn_s_sleep(1);
      __hip_atomic_store(grel, k, __ATOMIC_RELAXED, __HIP_MEMORY_SCOPE_AGENT);
    } else {
      while (__hip_atomic_load(grel, __ATOMIC_RELAXED, __HIP_MEMORY_SCOPE_AGENT) < k)
        __builtin_amdgcn_s_sleep(1);
    }
  }
  __syncthreads();
}

__device__ __forceinline__ float sigm(float x) { return 1.f / (1.f + expf(-x)); }
__device__ __forceinline__ float lrelu(float x) { return x >= 0.f ? x : 0.01f * x; }

__global__ __launch_bounds__(BT, 2) void dec_regw_kernel(Params p) {
  __shared__ float sx[5632];
  __shared__ float s_red[8];
  __shared__ float s_part[72];

  const int tid = threadIdx.x;
  const int lane = tid & 63;
  const int w = tid >> 6;            // wave 0..7
  const int b = blockIdx.x;
  const int gw = b * 8 + w;          // 0..2047
  const int i0 = b * 4;
  const int j0 = b * 8;

  // state arrays (all cross-block traffic via ald/ast); all within 64KB header
  float* h1w = p.ws + 2048;
  float* h2w = p.ws + 3072;
  float* qw = p.ws + 4096;
  float* evw = p.ws + 5120;   // 256
  float* ctxw = p.ws + 5376;  // 2048
  float* o1w = p.ws + 7424;
  float* o2w = p.ws + 8448;
  float* gh1 = p.ws + 9472;   // 3072
  float* gh2 = p.ws + 12544;  // 3072

  float* outs = p.out;            // 128*512
  float* pres = p.out + 65536;    // 128*1024
  float* alph = p.out + 196608;   // 128*256
  float* h1f = p.out + 229376;
  float* h2f = p.out + 230400;

  // ======== Register-resident weight load (once; fixed per wave for all t) ====
  // Phase A weights: 11 or 12 chunks per wave
  uint32 wa[48];
  if (gw < 1024) {
#pragma unroll
    for (int c = 0; c < 7; ++c)
      ldchunk(p.Wpre, (size_t)gw * 3584 + c * 512, lane, wa + 4 * c);
    ldchunk(p.Whh1, (size_t)gw * 1024, lane, wa + 28);
    ldchunk(p.Whh1, (size_t)gw * 1024 + 512, lane, wa + 32);
    ldchunk(p.Whh1, (size_t)(gw + 1024) * 1024, lane, wa + 36);
    ldchunk(p.Whh1, (size_t)(gw + 1024) * 1024 + 512, lane, wa + 40);
    wa[44] = wa[45] = wa[46] = wa[47] = 0u;
  } else {
    const int widx = gw - 1024;
    ldchunk(p.Whh1, (size_t)(2048 + widx) * 1024, lane, wa + 0);
    ldchunk(p.Whh1, (size_t)(2048 + widx) * 1024 + 512, lane, wa + 4);
#pragma unroll
    for (int r = 0; r < 3; ++r) {
      ldchunk(p.Whh2, (size_t)(widx + r * 1024) * 1024, lane, wa + 8 + 8 * r);
      ldchunk(p.Whh2, (size_t)(widx + r * 1024) * 1024 + 512, lane, wa + 12 + 8 * r);
    }
    ldchunk(p.Wq, (size_t)widx * 1024, lane, wa + 32);
    ldchunk(p.Wq, (size_t)widx * 1024 + 512, lane, wa + 36);
    const int wr = widx & 511;  // clamp; store is guarded by widx<512
    ldchunk(p.Wout, (size_t)wr * 1024, lane, wa + 40);
    ldchunk(p.Wout, (size_t)wr * 1024 + 512, lane, wa + 44);
  }

  // Phase D weights: Wih1, chunks mm = w+8k (mm<60)
  uint32 wd[32];
#pragma unroll
  for (int k = 0; k < 8; ++k) {
    const int mm = w + 8 * k;
    const int mmc = mm < 60 ? mm : 0;
    const int r = mmc / 15, m = mmc % 15, g = m / 5, c = m % 5;
    ldchunk(p.Wih1, (size_t)(g * 1024 + i0 + r) * 2560 + c * 512, lane, wd + 4 * k);
  }

  // Phase E weights: Wih2, chunks mm = w+8k (9 each, exact)
  uint32 we9[36];
#pragma unroll
  for (int k = 0; k < 9; ++k) {
    const int mm = w + 8 * k;
    const int r = mm / 18, m = mm % 18, g = m / 6, c = m % 6;
    ldchunk(p.Wih2, (size_t)(g * 1024 + i0 + r) * 3072 + c * 512, lane, we9 + 4 * k);
  }

  // Phase C: enc[tid, j0..j0+7] packed bf16 (threads 0..255)
  uint32 wenc[4] = {0u, 0u, 0u, 0u};
  if (tid < 256) {
    const float* er = p.enc + (size_t)tid * 2048 + j0;
    float4 a = *(const float4*)er, c = *(const float4*)(er + 4);
    wenc[0] = bfr(a.x) | (bfr(a.y) << 16);
    wenc[1] = bfr(a.z) | (bfr(a.w) << 16);
    wenc[2] = bfr(c.x) | (bfr(c.y) << 16);
    wenc[3] = bfr(c.z) | (bfr(c.w) << 16);
  }

  // Phase B: pk[b, 2*tid..2*tid+1] and v_att slice, fp32 in regs
  const int d0 = tid * 2;
  const float pk0 = p.pk[(size_t)b * 1024 + d0];
  const float pk1 = p.pk[(size_t)b * 1024 + d0 + 1];
  const float va0 = p.vatt[d0];
  const float va1 = p.vatt[d0 + 1];

  // init recurrent state (agent-scope stores)
  if (gw < 16) ast(h1w + gw * 64 + lane, p.h1_in[gw * 64 + lane]);
  else if (gw < 32) ast(h2w + (gw - 16) * 64 + lane, p.h2_in[(gw - 16) * 64 + lane]);

  int bk = 0;
  gbar(p.bar, ++bk);

  for (int t = 0; t <= NSTEP; ++t) {
    gbar(p.bar, ++bk);
    // ======== Phase A: epilogue(t-1) [pre,out] + q + gh1 + gh2 ========
    // sx: [0:512)=emb(t-1) | [512:1536)=o2 | [1536:3584)=ctx | [3584:4608)=h1 | [4608:5632)=h2
    {
      const float* embp = p.embeds + (size_t)p.inputs[t > 0 ? t - 1 : 0] * 512;
      for (int i = tid; i < 5632; i += BT) {
        float v;
        if (i < 512) v = embp[i];
        else if (i < 1536) v = ald(o2w + i - 512);
        else if (i < 3584) v = ald(ctxw + i - 1536);
        else if (i < 4608) v = ald(h1w + i - 3584);
        else v = ald(h2w + i - 4608);
        sx[i] = v;
      }
      __syncthreads();
      if (gw < 1024) {
        if (t > 0) {  // pre row gw (K=3584)
          float s = 0.f;
#pragma unroll
          for (int c = 0; c < 7; ++c) s += dotchunk(wa + 4 * c, sx + 512 * c, lane);
          s = wsum(s);
          if (lane == 0) pres[(size_t)(t - 1) * 1024 + gw] = lrelu(s + p.bpre[gw]);
        }
        float s1 = dotchunk(wa + 28, sx + 3584, lane) + dotchunk(wa + 32, sx + 4096, lane);
        s1 = wsum(s1);
        if (lane == 0) ast(gh1 + gw, s1 + p.bhh1[gw]);
        float s2 = dotchunk(wa + 36, sx + 3584, lane) + dotchunk(wa + 40, sx + 4096, lane);
        s2 = wsum(s2);
        if (lane == 0) ast(gh1 + 1024 + gw, s2 + p.bhh1[1024 + gw]);
      } else {
        const int widx = gw - 1024;
        float s = dotchunk(wa + 0, sx + 3584, lane) + dotchunk(wa + 4, sx + 4096, lane);
        s = wsum(s);
        if (lane == 0) ast(gh1 + 2048 + widx, s + p.bhh1[2048 + widx]);
#pragma unroll
        for (int r = 0; r < 3; ++r) {
          float t2 = dotchunk(wa + 8 + 8 * r, sx + 4608, lane) +
                     dotchunk(wa + 12 + 8 * r, sx + 5120, lane);
          t2 = wsum(t2);
          if (lane == 0) ast(gh2 + widx + 1024 * r, t2 + p.bhh2[widx + 1024 * r]);
        }
        float sq = dotchunk(wa + 32, sx + 4608, lane) + dotchunk(wa + 36, sx + 5120, lane);
        sq = wsum(sq);
        if (lane == 0) ast(qw + widx, sq);
        if (t > 0 && widx < 512) {  // out row widx (wave-uniform branch)
          float so = dotchunk(wa + 40, sx + 512, lane) + dotchunk(wa + 44, sx + 1024, lane);
          so = wsum(so);
          if (lane == 0) outs[(size_t)(t - 1) * 512 + widx] = so + p.bout[widx];
        }
      }
    }
    if (t == NSTEP) break;

    gbar(p.bar, ++bk);
    // ======== Phase B: e[b] = tanh(pk[b,:]+q)·v, all 8 waves (2 dims/thread) ====
    {
      float q0 = ald(qw + d0), q1 = ald(qw + d0 + 1);
      float acc = va0 * tanhf(pk0 + q0) + va1 * tanhf(pk1 + q1);
      acc = wsum(acc);
      if (lane == 0) s_red[w] = acc;
      __syncthreads();
      if (tid == 0) {
        float e = s_red[0] + s_red[1] + s_red[2] + s_red[3] +
                  s_red[4] + s_red[5] + s_red[6] + s_red[7];
        ast(evw + b, e);
      }
    }

    gbar(p.bar, ++bk);
    // ======== Phase C: softmax (redundant/block, tid<256) + 8 ctx cols/block ====
    {
      float e_i = 0.f, pe = 0.f;
      if (tid < 256) {
        e_i = ald(evw + tid);
        float mw = e_i;
#pragma unroll
        for (int o = 32; o; o >>= 1) mw = fmaxf(mw, __shfl_xor(mw, o, 64));
        if (lane == 0) s_red[w] = mw;
      }
      __syncthreads();
      float m = fmaxf(fmaxf(s_red[0], s_red[1]), fmaxf(s_red[2], s_red[3]));
      __syncthreads();
      if (tid < 256) {
        pe = expf(e_i - m);
        float zw = wsum(pe);
        if (lane == 0) s_red[w] = zw;
      }
      __syncthreads();
      float Z = s_red[0] + s_red[1] + s_red[2] + s_red[3];
      if (tid < 256) {
        float alpha = pe / Z;
        if (b == 0) alph[(size_t)t * 256 + tid] = alpha;
        sx[tid * 8 + 0] = alpha * blo(wenc[0]);
        sx[tid * 8 + 1] = alpha * bhi(wenc[0]);
        sx[tid * 8 + 2] = alpha * blo(wenc[1]);
        sx[tid * 8 + 3] = alpha * bhi(wenc[1]);
        sx[tid * 8 + 4] = alpha * blo(wenc[2]);
        sx[tid * 8 + 5] = alpha * bhi(wenc[2]);
        sx[tid * 8 + 6] = alpha * blo(wenc[3]);
        sx[tid * 8 + 7] = alpha * bhi(wenc[3]);
      }
      __syncthreads();
      for (int st = 128; st >= 1; st >>= 1) {
        if (tid < st) {
#pragma unroll
          for (int j = 0; j < 8; ++j) sx[tid * 8 + j] += sx[(tid + st) * 8 + j];
        }
        __syncthreads();
      }
      if (tid < 8) ast(ctxw + j0 + tid, sx[tid]);
    }

    gbar(p.bar, ++bk);
    // ======== Phase D: GRU1, block owns i0..i0+3; x=[emb|ctx] (2560) ========
    {
      const float* embc = p.embeds + (size_t)p.inputs[t] * 512;
      for (int i = tid; i < 2560; i += BT)
        sx[i] = (i < 512) ? embc[i] : ald(ctxw + i - 512);
      __syncthreads();
#pragma unroll
      for (int k = 0; k < 8; ++k) {
        const int mm = w + 8 * k;
        if (mm < 60) {  // wave-uniform
          const int c = (mm % 15) % 5;
          float s = dotchunk(wd + 4 * k, sx + c * 512, lane);
          s = wsum(s);
          if (lane == 0) s_part[mm] = s;
        }
      }
      __syncthreads();
      if (tid < 4) {
        const int i = i0 + tid;
        const float* sp = s_part + tid * 15;
        float sr = sp[0] + sp[1] + sp[2] + sp[3] + sp[4];
        float sz = sp[5] + sp[6] + sp[7] + sp[8] + sp[9];
        float sn = sp[10] + sp[11] + sp[12] + sp[13] + sp[14];
        float r = sigm(sr + p.bih1[i] + ald(gh1 + i));
        float z = sigm(sz + p.bih1[1024 + i] + ald(gh1 + 1024 + i));
        float n = tanhf(sn + p.bih1[2048 + i] + r * ald(gh1 + 2048 + i));
        float h = (1.f - z) * n + z * ald(h1w + i);
        ast(h1w + i, h);
        ast(o1w + i, lrelu(h));
      }
    }

    gbar(p.bar, ++bk);
    // ======== Phase E: GRU2, block owns i0..i0+3; x=[o1|ctx] (3072) ========
    {
      for (int i = tid; i < 3072; i += BT)
        sx[i] = (i < 1024) ? ald(o1w + i) : ald(ctxw + i - 1024);
      __syncthreads();
#pragma unroll
      for (int k = 0; k < 9; ++k) {
        const int mm = w + 8 * k;  // < 72 always
        const int c = (mm % 18) % 6;
        float s = dotchunk(we9 + 4 * k, sx + c * 512, lane);
        s = wsum(s);
        if (lane == 0) s_part[mm] = s;
      }
      __syncthreads();
      if (tid < 4) {
        const int i = i0 + tid;
        const float* sp = s_part + tid * 18;
        float sr = sp[0] + sp[1] + sp[2] + sp[3] + sp[4] + sp[5];
        float sz = sp[6] + sp[7] + sp[8] + sp[9] + sp[10] + sp[11];
        float sn = sp[12] + sp[13] + sp[14] + sp[15] + sp[16] + sp[17];
        float r = sigm(sr + p.bih2[i] + ald(gh2 + i));
        float z = sigm(sz + p.bih2[1024 + i] + ald(gh2 + 1024 + i));
        float n = tanhf(sn + p.bih2[2048 + i] + r * ald(gh2 + 2048 + i));
        float h = (1.f - z) * n + z * ald(h2w + i);
        ast(h2w + i, h);
        ast(o2w + i, lrelu(h));
      }
    }
  }
  // ======== Final state outputs ========
  if (gw < 16) h1f[gw * 64 + lane] = ald(h1w + gw * 64 + lane);
  else if (gw < 32) h2f[(gw - 16) * 64 + lane] = ald(h2w + (gw - 16) * 64 + lane);
}

extern "C" void kernel_launch(void* const* d_in, const int* in_sizes, int n_in,
                              void* d_out, int out_size, void* d_ws, size_t ws_size,
                              hipStream_t stream) {
  hipMemsetAsync(d_ws, 0, 65536, stream);  // barrier lines + state region

  Params p;
  p.inputs = (const int*)d_in[0];
  p.h1_in = (const float*)d_in[1];
  p.h2_in = (const float*)d_in[2];
  p.pk = (const float*)d_in[3];
  p.enc = (const float*)d_in[4];
  p.embeds = (const float*)d_in[5];
  p.Wq = (const float*)d_in[6];
  p.vatt = (const float*)d_in[7];
  p.Wih1 = (const float*)d_in[8];
  p.Whh1 = (const float*)d_in[9];
  p.bih1 = (const float*)d_in[10];
  p.bhh1 = (const float*)d_in[11];
  p.Wih2 = (const float*)d_in[12];
  p.Whh2 = (const float*)d_in[13];
  p.bih2 = (const float*)d_in[14];
  p.bhh2 = (const float*)d_in[15];
  p.Wpre = (const float*)d_in[16];
  p.bpre = (const float*)d_in[17];
  p.Wout = (const float*)d_in[18];
  p.bout = (const float*)d_in[19];
  p.out = (float*)d_out;
  p.ws = (float*)d_ws;
  p.bar = (int*)d_ws;

  void* args[] = {&p};
  hipError_t err = hipLaunchCooperativeKernel((const void*)dec_regw_kernel,
                                              dim3(GBLK), dim3(BT), args, 0, stream);
  if (err != hipSuccess) {
    // Fallback: plain launch. 256 blocks at 1 block/CU are trivially co-resident,
    // so the custom barrier remains safe.
    dec_regw_kernel<<<dim3(GBLK), dim3(BT), 0, stream>>>(p);
  }
}

// Round 2
// 6433.561 us; speedup vs baseline: 1.1252x; 1.1252x over previous
//
#include <hip/hip_runtime.h>

typedef unsigned int uint32;
typedef unsigned long long u64;

#define GBLK 256
#define BT 512
#define NSTEP 128

// ws u64-array offsets (in u64 units). All cross-block state is epoch-tagged:
// u64 = (epoch << 32) | f32bits. Produced-in-step-t values carry tag t+2;
// initial state carries tag 1 (== "produced in step -1"). Single 8B relaxed
// agent-scope stores make tag+value atomic -> no fences, no barriers, no wbl2.
#define QE    0
#define EE    1024
#define CTXE  1280
#define H1E   3328
#define H2E   4352
#define O1E   5376
#define O2E   6400
#define GH1E  7424
#define GH2E  10496
// total 13568 u64 = 108544 B

struct Params {
  const int* inputs;
  const float *h1_in, *h2_in, *embeds, *vatt;
  const float *pk, *enc, *Wq, *Wih1, *Whh1, *Wih2, *Whh2, *Wpre, *Wout;
  const float *bih1, *bhh1, *bih2, *bhh2, *bpre, *bout;
  float* out;
  float* ws;
};

__device__ __forceinline__ float blo(uint32 u) { return __uint_as_float(u << 16); }
__device__ __forceinline__ float bhi(uint32 u) { return __uint_as_float(u & 0xffff0000u); }
__device__ __forceinline__ uint32 bfr(float f) {  // fp32 -> bf16 bits, RNE
  uint32 u = __float_as_uint(f);
  return (u + 0x7fffu + ((u >> 16) & 1u)) >> 16;
}

__device__ __forceinline__ u64 ald64(const u64* a) {
  return __hip_atomic_load(a, __ATOMIC_RELAXED, __HIP_MEMORY_SCOPE_AGENT);
}
__device__ __forceinline__ void ast64(u64* a, u64 v) {
  __hip_atomic_store(a, v, __ATOMIC_RELAXED, __HIP_MEMORY_SCOPE_AGENT);
}
__device__ __forceinline__ u64 pk64(float f, uint32 ep) {
  return ((u64)ep << 32) | (u64)__float_as_uint(f);
}
__device__ __forceinline__ float lo32f(u64 v) { return __uint_as_float((uint32)v); }
__device__ __forceinline__ bool tok(u64 v, uint32 tg) { return (uint32)(v >> 32) >= tg; }

__device__ __forceinline__ float wsum(float v) {
#pragma unroll
  for (int o = 32; o; o >>= 1) v += __shfl_xor(v, o, 64);
  return v;
}

// Load one 512-elem chunk (this lane's 8-elem slice) of fp32 W, pack into
// 4 registers of 2xbf16. Done ONCE; weights live in VGPRs for all 128 steps.
__device__ __forceinline__ void ldchunk(const float* W, size_t base, int lane, uint32* r) {
  const float* wf = W + base + lane * 8;
  float4 a = *(const float4*)wf;
  float4 c = *(const float4*)(wf + 4);
  r[0] = bfr(a.x) | (bfr(a.y) << 16);
  r[1] = bfr(a.z) | (bfr(a.w) << 16);
  r[2] = bfr(c.x) | (bfr(c.y) << 16);
  r[3] = bfr(c.z) | (bfr(c.w) << 16);
}

__device__ __forceinline__ float dotchunk(const uint32* r, const float* xc, int lane) {
  const float* x = xc + lane * 8;
  float4 x0 = *(const float4*)x, x1 = *(const float4*)(x + 4);
  return blo(r[0]) * x0.x + bhi(r[0]) * x0.y + blo(r[1]) * x0.z + bhi(r[1]) * x0.w +
         blo(r[2]) * x1.x + bhi(r[2]) * x1.y + blo(r[3]) * x1.z + bhi(r[3]) * x1.w;
}

__device__ __forceinline__ float sigm(float x) { return 1.f / (1.f + expf(-x)); }
__device__ __forceinline__ float lrelu(float x) { return x >= 0.f ? x : 0.01f * x; }

__global__ __launch_bounds__(BT, 2) void dec_flow_kernel(Params p) {
  __shared__ float sx[8192];   // [0:3584) A2/D/E x | [6144:7168) h1 | [7168:8192) h2
  __shared__ float s_red[8];
  __shared__ float s_part[72];

  const int tid = threadIdx.x;
  const int lane = tid & 63;
  const int w = tid >> 6;            // wave 0..7
  const int b = blockIdx.x;
  const int gw = b * 8 + w;          // 0..2047
  const int i0 = b * 4;
  const int j0 = b * 8;

  u64* wsu = (u64*)p.ws;

  float* outs = p.out;            // 128*512
  float* pres = p.out + 65536;    // 128*1024
  float* alph = p.out + 196608;   // 128*256
  float* h1f = p.out + 229376;
  float* h2f = p.out + 230400;

  // ======== Register-resident weight load (once; fixed per wave for all t) ====
  uint32 wa[48];
  if (gw < 1024) {
#pragma unroll
    for (int c = 0; c < 7; ++c)
      ldchunk(p.Wpre, (size_t)gw * 3584 + c * 512, lane, wa + 4 * c);
    ldchunk(p.Whh1, (size_t)gw * 1024, lane, wa + 28);
    ldchunk(p.Whh1, (size_t)gw * 1024 + 512, lane, wa + 32);
    ldchunk(p.Whh1, (size_t)(gw + 1024) * 1024, lane, wa + 36);
    ldchunk(p.Whh1, (size_t)(gw + 1024) * 1024 + 512, lane, wa + 40);
    wa[44] = wa[45] = wa[46] = wa[47] = 0u;
  } else {
    const int widx = gw - 1024;
    ldchunk(p.Whh1, (size_t)(2048 + widx) * 1024, lane, wa + 0);
    ldchunk(p.Whh1, (size_t)(2048 + widx) * 1024 + 512, lane, wa + 4);
#pragma unroll
    for (int r = 0; r < 3; ++r) {
      ldchunk(p.Whh2, (size_t)(widx + r * 1024) * 1024, lane, wa + 8 + 8 * r);
      ldchunk(p.Whh2, (size_t)(widx + r * 1024) * 1024 + 512, lane, wa + 12 + 8 * r);
    }
    ldchunk(p.Wq, (size_t)widx * 1024, lane, wa + 32);
    ldchunk(p.Wq, (size_t)widx * 1024 + 512, lane, wa + 36);
    const int wr = widx & 511;  // clamp; store guarded by widx<512
    ldchunk(p.Wout, (size_t)wr * 1024, lane, wa + 40);
    ldchunk(p.Wout, (size_t)wr * 1024 + 512, lane, wa + 44);
  }

  uint32 wd[32];
#pragma unroll
  for (int k = 0; k < 8; ++k) {
    const int mm = w + 8 * k;
    const int mmc = mm < 60 ? mm : 0;
    const int r = mmc / 15, m = mmc % 15, g = m / 5, c = m % 5;
    ldchunk(p.Wih1, (size_t)(g * 1024 + i0 + r) * 2560 + c * 512, lane, wd + 4 * k);
  }

  uint32 we9[36];
#pragma unroll
  for (int k = 0; k < 9; ++k) {
    const int mm = w + 8 * k;
    const int r = mm / 18, m = mm % 18, g = m / 6, c = m % 6;
    ldchunk(p.Wih2, (size_t)(g * 1024 + i0 + r) * 3072 + c * 512, lane, we9 + 4 * k);
  }

  uint32 wenc[4] = {0u, 0u, 0u, 0u};
  if (tid < 256) {
    const float* er = p.enc + (size_t)tid * 2048 + j0;
    float4 a = *(const float4*)er, c = *(const float4*)(er + 4);
    wenc[0] = bfr(a.x) | (bfr(a.y) << 16);
    wenc[1] = bfr(a.z) | (bfr(a.w) << 16);
    wenc[2] = bfr(c.x) | (bfr(c.y) << 16);
    wenc[3] = bfr(c.z) | (bfr(c.w) << 16);
  }

  const int d0 = tid * 2;
  const float pk0 = p.pk[(size_t)b * 1024 + d0];
  const float pk1 = p.pk[(size_t)b * 1024 + d0 + 1];
  const float va0 = p.vatt[d0];
  const float va1 = p.vatt[d0 + 1];

  // init recurrent state with tag 1
  if (gw < 16) ast64(wsu + H1E + gw * 64 + lane, pk64(p.h1_in[gw * 64 + lane], 1));
  else if (gw < 32) ast64(wsu + H2E + (gw - 16) * 64 + lane, pk64(p.h2_in[(gw - 16) * 64 + lane], 1));

  for (int t = 0; t <= NSTEP; ++t) {
    const uint32 TP = (uint32)(t + 1);  // tag of prev-step state
    const uint32 TS = (uint32)(t + 2);  // tag of values produced this step

    // ======== Phase A stage-1: poll h1,h2 into LDS; compute q/gh1/gh2 ========
    if (t < NSTEP) {
      {
        const u64 *a0 = wsu + H1E + tid, *a1 = wsu + H1E + 512 + tid;
        const u64 *a2 = wsu + H2E + tid, *a3 = wsu + H2E + 512 + tid;
        u64 v0, v1, v2, v3;
        for (;;) {
          v0 = ald64(a0); v1 = ald64(a1); v2 = ald64(a2); v3 = ald64(a3);
          if (tok(v0, TP) && tok(v1, TP) && tok(v2, TP) && tok(v3, TP)) break;
          __builtin_amdgcn_s_sleep(1);
        }
        sx[6144 + tid] = lo32f(v0); sx[6656 + tid] = lo32f(v1);
        sx[7168 + tid] = lo32f(v2); sx[7680 + tid] = lo32f(v3);
      }
      __syncthreads();
      if (gw >= 1024) {
        const int widx = gw - 1024;
        // q FIRST (critical path)
        float sq = dotchunk(wa + 32, sx + 7168, lane) + dotchunk(wa + 36, sx + 7680, lane);
        sq = wsum(sq);
        if (lane == 0) ast64(wsu + QE + widx, pk64(sq, TS));
        float s = dotchunk(wa + 0, sx + 6144, lane) + dotchunk(wa + 4, sx + 6656, lane);
        s = wsum(s);
        if (lane == 0) ast64(wsu + GH1E + 2048 + widx, pk64(s + p.bhh1[2048 + widx], TS));
#pragma unroll
        for (int r = 0; r < 3; ++r) {
          float t2 = dotchunk(wa + 8 + 8 * r, sx + 7168, lane) +
                     dotchunk(wa + 12 + 8 * r, sx + 7680, lane);
          t2 = wsum(t2);
          if (lane == 0) ast64(wsu + GH2E + widx + 1024 * r, pk64(t2 + p.bhh2[widx + 1024 * r], TS));
        }
      } else {
        float s1 = dotchunk(wa + 28, sx + 6144, lane) + dotchunk(wa + 32, sx + 6656, lane);
        s1 = wsum(s1);
        if (lane == 0) ast64(wsu + GH1E + gw, pk64(s1 + p.bhh1[gw], TS));
        float s2 = dotchunk(wa + 36, sx + 6144, lane) + dotchunk(wa + 40, sx + 6656, lane);
        s2 = wsum(s2);
        if (lane == 0) ast64(wsu + GH1E + 1024 + gw, pk64(s2 + p.bhh1[1024 + gw], TS));
      }
    }

    // ======== Phase A stage-2: epilogue(t-1) pre + out ========
    if (t > 0) {
      {
        const float* embp = p.embeds + (size_t)p.inputs[t - 1] * 512;
        float ev = embp[tid];
        const u64 *a0 = wsu + O2E + tid, *a1 = wsu + O2E + 512 + tid;
        const u64 *c0 = wsu + CTXE + tid, *c1 = wsu + CTXE + 512 + tid;
        const u64 *c2 = wsu + CTXE + 1024 + tid, *c3 = wsu + CTXE + 1536 + tid;
        u64 v0, v1, u0, u1, u2, u3;
        for (;;) {
          v0 = ald64(a0); v1 = ald64(a1);
          u0 = ald64(c0); u1 = ald64(c1); u2 = ald64(c2); u3 = ald64(c3);
          if (tok(v0, TP) && tok(v1, TP) && tok(u0, TP) && tok(u1, TP) &&
              tok(u2, TP) && tok(u3, TP)) break;
          __builtin_amdgcn_s_sleep(1);
        }
        sx[tid] = ev;
        sx[512 + tid] = lo32f(v0); sx[1024 + tid] = lo32f(v1);
        sx[1536 + tid] = lo32f(u0); sx[2048 + tid] = lo32f(u1);
        sx[2560 + tid] = lo32f(u2); sx[3072 + tid] = lo32f(u3);
      }
      __syncthreads();
      if (gw < 1024) {
        float s = 0.f;
#pragma unroll
        for (int c = 0; c < 7; ++c) s += dotchunk(wa + 4 * c, sx + 512 * c, lane);
        s = wsum(s);
        if (lane == 0) pres[(size_t)(t - 1) * 1024 + gw] = lrelu(s + p.bpre[gw]);
      } else if (gw - 1024 < 512) {
        const int widx = gw - 1024;
        float so = dotchunk(wa + 40, sx + 512, lane) + dotchunk(wa + 44, sx + 1024, lane);
        so = wsum(so);
        if (lane == 0) outs[(size_t)(t - 1) * 512 + widx] = so + p.bout[widx];
      }
    }
    if (t == NSTEP) break;

    // ======== Phase C: e[b] + softmax + ctx (merged; dataflow-synced) ========
    {
      float q0, q1;
      {
        const u64 *a0 = wsu + QE + d0, *a1 = wsu + QE + d0 + 1;
        u64 v0, v1;
        for (;;) {
          v0 = ald64(a0); v1 = ald64(a1);
          if (tok(v0, TS) && tok(v1, TS)) break;
          __builtin_amdgcn_s_sleep(1);
        }
        q0 = lo32f(v0); q1 = lo32f(v1);
      }
      float acc = va0 * tanhf(pk0 + q0) + va1 * tanhf(pk1 + q1);
      acc = wsum(acc);
      if (lane == 0) s_red[w] = acc;
      __syncthreads();
      if (tid == 0) {
        float e = s_red[0] + s_red[1] + s_red[2] + s_red[3] +
                  s_red[4] + s_red[5] + s_red[6] + s_red[7];
        ast64(wsu + EE + b, pk64(e, TS));
      }
      __syncthreads();  // protect s_red before reuse
      float e_i = 0.f, pe = 0.f;
      if (tid < 256) {
        u64 v = ald64(wsu + EE + tid);
        while (!tok(v, TS)) { __builtin_amdgcn_s_sleep(1); v = ald64(wsu + EE + tid); }
        e_i = lo32f(v);
        float mw = e_i;
#pragma unroll
        for (int o = 32; o; o >>= 1) mw = fmaxf(mw, __shfl_xor(mw, o, 64));
        if (lane == 0) s_red[w] = mw;
      }
      __syncthreads();
      float m = fmaxf(fmaxf(s_red[0], s_red[1]), fmaxf(s_red[2], s_red[3]));
      __syncthreads();
      if (tid < 256) {
        pe = expf(e_i - m);
        float zw = wsum(pe);
        if (lane == 0) s_red[w] = zw;
      }
      __syncthreads();
      float Z = s_red[0] + s_red[1] + s_red[2] + s_red[3];
      if (tid < 256) {
        float alpha = pe / Z;
        if (b == 0) alph[(size_t)t * 256 + tid] = alpha;
        float c[8];
        c[0] = alpha * blo(wenc[0]); c[1] = alpha * bhi(wenc[0]);
        c[2] = alpha * blo(wenc[1]); c[3] = alpha * bhi(wenc[1]);
        c[4] = alpha * blo(wenc[2]); c[5] = alpha * bhi(wenc[2]);
        c[6] = alpha * blo(wenc[3]); c[7] = alpha * bhi(wenc[3]);
#pragma unroll
        for (int o = 32; o; o >>= 1) {
#pragma unroll
          for (int j = 0; j < 8; ++j) c[j] += __shfl_xor(c[j], o, 64);
        }
        if (lane == 0) {
#pragma unroll
          for (int j = 0; j < 8; ++j) s_part[w * 8 + j] = c[j];
        }
      }
      __syncthreads();
      if (tid < 8) {
        float cj = s_part[tid] + s_part[8 + tid] + s_part[16 + tid] + s_part[24 + tid];
        ast64(wsu + CTXE + j0 + tid, pk64(cj, TS));
      }
    }

    // ======== Phase D: GRU1; x=[emb|ctx] in sx[0:2560) ========
    {
      float g1a = 0.f, g1b = 0.f, g1c = 0.f, h1old = 0.f;
      if (tid < 4) {
        const int i = i0 + tid;
        u64 x0, x1, x2;
        for (;;) {
          x0 = ald64(wsu + GH1E + i); x1 = ald64(wsu + GH1E + 1024 + i);
          x2 = ald64(wsu + GH1E + 2048 + i);
          if (tok(x0, TS) && tok(x1, TS) && tok(x2, TS)) break;
          __builtin_amdgcn_s_sleep(1);
        }
        g1a = lo32f(x0); g1b = lo32f(x1); g1c = lo32f(x2);
        h1old = sx[6144 + i];
      }
      {
        const float* embc = p.embeds + (size_t)p.inputs[t] * 512;
        float ev = embc[tid];
        const u64 *c0 = wsu + CTXE + tid, *c1 = wsu + CTXE + 512 + tid;
        const u64 *c2 = wsu + CTXE + 1024 + tid, *c3 = wsu + CTXE + 1536 + tid;
        u64 u0, u1, u2, u3;
        for (;;) {
          u0 = ald64(c0); u1 = ald64(c1); u2 = ald64(c2); u3 = ald64(c3);
          if (tok(u0, TS) && tok(u1, TS) && tok(u2, TS) && tok(u3, TS)) break;
          __builtin_amdgcn_s_sleep(1);
        }
        sx[tid] = ev;
        sx[512 + tid] = lo32f(u0); sx[1024 + tid] = lo32f(u1);
        sx[1536 + tid] = lo32f(u2); sx[2048 + tid] = lo32f(u3);
      }
      __syncthreads();
#pragma unroll
      for (int k = 0; k < 8; ++k) {
        const int mm = w + 8 * k;
        if (mm < 60) {  // wave-uniform
          const int c = (mm % 15) % 5;
          float s = dotchunk(wd + 4 * k, sx + c * 512, lane);
          s = wsum(s);
          if (lane == 0) s_part[mm] = s;
        }
      }
      __syncthreads();
      if (tid < 4) {
        const int i = i0 + tid;
        const float* sp = s_part + tid * 15;
        float sr = sp[0] + sp[1] + sp[2] + sp[3] + sp[4];
        float sz = sp[5] + sp[6] + sp[7] + sp[8] + sp[9];
        float sn = sp[10] + sp[11] + sp[12] + sp[13] + sp[14];
        float r = sigm(sr + p.bih1[i] + g1a);
        float z = sigm(sz + p.bih1[1024 + i] + g1b);
        float n = tanhf(sn + p.bih1[2048 + i] + r * g1c);
        float h = (1.f - z) * n + z * h1old;
        ast64(wsu + H1E + i, pk64(h, TS));
        ast64(wsu + O1E + i, pk64(lrelu(h), TS));
      }
    }

    // ======== Phase E: GRU2; x = [o1 @ sx[2560:3584) | ctx @ sx[512:2560)] ====
    {
      float g2a = 0.f, g2b = 0.f, g2c = 0.f, h2old = 0.f;
      if (tid < 4) {
        const int i = i0 + tid;
        u64 x0, x1, x2;
        for (;;) {
          x0 = ald64(wsu + GH2E + i); x1 = ald64(wsu + GH2E + 1024 + i);
          x2 = ald64(wsu + GH2E + 2048 + i);
          if (tok(x0, TS) && tok(x1, TS) && tok(x2, TS)) break;
          __builtin_amdgcn_s_sleep(1);
        }
        g2a = lo32f(x0); g2b = lo32f(x1); g2c = lo32f(x2);
        h2old = sx[7168 + i];
      }
      {
        const u64 *a0 = wsu + O1E + tid, *a1 = wsu + O1E + 512 + tid;
        u64 v0, v1;
        for (;;) {
          v0 = ald64(a0); v1 = ald64(a1);
          if (tok(v0, TS) && tok(v1, TS)) break;
          __builtin_amdgcn_s_sleep(1);
        }
        sx[2560 + tid] = lo32f(v0); sx[3072 + tid] = lo32f(v1);
      }
      __syncthreads();
#pragma unroll
      for (int k = 0; k < 9; ++k) {
        const int mm = w + 8 * k;  // < 72 always
        const int c = (mm % 18) % 6;
        const float* xp = (c < 2) ? (sx + 2560 + c * 512) : (sx + 512 + (c - 2) * 512);
        float s = dotchunk(we9 + 4 * k, xp, lane);
        s = wsum(s);
        if (lane == 0) s_part[mm] = s;
      }
      __syncthreads();
      if (tid < 4) {
        const int i = i0 + tid;
        const float* sp = s_part + tid * 18;
        float sr = sp[0] + sp[1] + sp[2] + sp[3] + sp[4] + sp[5];
        float sz = sp[6] + sp[7] + sp[8] + sp[9] + sp[10] + sp[11];
        float sn = sp[12] + sp[13] + sp[14] + sp[15] + sp[16] + sp[17];
        float r = sigm(sr + p.bih2[i] + g2a);
        float z = sigm(sz + p.bih2[1024 + i] + g2b);
        float n = tanhf(sn + p.bih2[2048 + i] + r * g2c);
        float h = (1.f - z) * n + z * h2old;
        ast64(wsu + H2E + i, pk64(h, TS));
        ast64(wsu + O2E + i, pk64(lrelu(h), TS));
      }
    }
  }

  // ======== Final state outputs ========
  if (gw < 16) {
    u64 v = ald64(wsu + H1E + gw * 64 + lane);
    while (!tok(v, NSTEP + 1)) { __builtin_amdgcn_s_sleep(1); v = ald64(wsu + H1E + gw * 64 + lane); }
    h1f[gw * 64 + lane] = lo32f(v);
  } else if (gw < 32) {
    u64 v = ald64(wsu + H2E + (gw - 16) * 64 + lane);
    while (!tok(v, NSTEP + 1)) { __builtin_amdgcn_s_sleep(1); v = ald64(wsu + H2E + (gw - 16) * 64 + lane); }
    h2f[(gw - 16) * 64 + lane] = lo32f(v);
  }
}

extern "C" void kernel_launch(void* const* d_in, const int* in_sizes, int n_in,
                              void* d_out, int out_size, void* d_ws, size_t ws_size,
                              hipStream_t stream) {
  hipMemsetAsync(d_ws, 0, 131072, stream);  // zero all epoch tags

  Params p;
  p.inputs = (const int*)d_in[0];
  p.h1_in = (const float*)d_in[1];
  p.h2_in = (const float*)d_in[2];
  p.pk = (const float*)d_in[3];
  p.enc = (const float*)d_in[4];
  p.embeds = (const float*)d_in[5];
  p.Wq = (const float*)d_in[6];
  p.vatt = (const float*)d_in[7];
  p.Wih1 = (const float*)d_in[8];
  p.Whh1 = (const float*)d_in[9];
  p.bih1 = (const float*)d_in[10];
  p.bhh1 = (const float*)d_in[11];
  p.Wih2 = (const float*)d_in[12];
  p.Whh2 = (const float*)d_in[13];
  p.bih2 = (const float*)d_in[14];
  p.bhh2 = (const float*)d_in[15];
  p.Wpre = (const float*)d_in[16];
  p.bpre = (const float*)d_in[17];
  p.Wout = (const float*)d_in[18];
  p.bout = (const float*)d_in[19];
  p.out = (float*)d_out;
  p.ws = (float*)d_ws;

  void* args[] = {&p};
  hipError_t err = hipLaunchCooperativeKernel((const void*)dec_flow_kernel,
                                              dim3(GBLK), dim3(BT), args, 0, stream);
  if (err != hipSuccess) {
    // Fallback: plain launch. 256 blocks at 1 block/CU are trivially co-resident,
    // so the dataflow polling remains safe.
    dec_flow_kernel<<<dim3(GBLK), dim3(BT), 0, stream>>>(p);
  }
}

// Round 4
// 6060.564 us; speedup vs baseline: 1.1944x; 1.0615x over previous
//
#include <hip/hip_runtime.h>

typedef unsigned int uint32;

#define GBLK 256
#define BT 512
#define NSTEP 128

// ---- workspace layout ----
// int counters: 6 counters x 8 lanes (64B apart), region [0, 1024) ints.
#define CQ   0
#define CGH  1
#define CE   2
#define CCTX 3
#define CH1  4
#define CH2  5
// float data (untagged fp32), float indices:
#define QF    1024
#define EF    2048
#define CTXF  2304
#define H1FO  4352
#define H2FO  5376
#define O1F   6400
#define O2F   7424
#define GH1F  8448
#define GH2F  12544
// end 16640 floats = 66.5 KB

struct Params {
  const int* inputs;
  const float *h1_in, *h2_in, *embeds, *vatt;
  const float *pk, *enc, *Wq, *Wih1, *Whh1, *Wih2, *Whh2, *Wpre, *Wout;
  const float *bih1, *bhh1, *bih2, *bhh2, *bpre, *bout;
  float* out;
  float* ws;
};

__device__ __forceinline__ float blo(uint32 u) { return __uint_as_float(u << 16); }
__device__ __forceinline__ float bhi(uint32 u) { return __uint_as_float(u & 0xffff0000u); }
__device__ __forceinline__ uint32 bfr(float f) {  // fp32 -> bf16 bits, RNE
  uint32 u = __float_as_uint(f);
  return (u + 0x7fffu + ((u >> 16) & 1u)) >> 16;
}

// agent-scope (MALL-coherent) scalar access
__device__ __forceinline__ float ald(const float* a) {
  return __hip_atomic_load(a, __ATOMIC_RELAXED, __HIP_MEMORY_SCOPE_AGENT);
}
__device__ __forceinline__ void ast(float* a, float v) {
  __hip_atomic_store(a, v, __ATOMIC_RELAXED, __HIP_MEMORY_SCOPE_AGENT);
}

// 16B device-coherent load (bypass L1/L2 -> MALL)
__device__ __forceinline__ float4 cld16(const float* p) {
  float4 r;
  asm volatile("global_load_dwordx4 %0, %1, off sc0 sc1\n\ts_waitcnt vmcnt(0)"
               : "=&v"(r) : "v"(p) : "memory");
  return r;
}

// drain this wave's outstanding stores (manual release, no wbL2)
#define VDRAIN() asm volatile("s_waitcnt vmcnt(0)" ::: "memory")

__device__ __forceinline__ void cadd(int* wsi, int c, int b) {
  __hip_atomic_fetch_add(wsi + c * 128 + (b & 7) * 16, 1,
                         __ATOMIC_RELAXED, __HIP_MEMORY_SCOPE_AGENT);
}
__device__ __forceinline__ void cpoll(const int* wsi, int c, int tgt) {
  const int* base = wsi + c * 128;
  for (;;) {
    bool ok = true;
#pragma unroll
    for (int k = 0; k < 8; ++k)
      ok &= (__hip_atomic_load(base + k * 16, __ATOMIC_RELAXED,
                               __HIP_MEMORY_SCOPE_AGENT) >= tgt);
    if (ok) return;
    __builtin_amdgcn_s_sleep(1);
  }
}

__device__ __forceinline__ float wsum(float v) {
#pragma unroll
  for (int o = 32; o; o >>= 1) v += __shfl_xor(v, o, 64);
  return v;
}

// one-time fp32->bf16x2 packed weight chunk load (stays in VGPRs all 128 steps)
__device__ __forceinline__ void ldchunk(const float* W, size_t base, int lane, uint32* r) {
  const float* wf = W + base + lane * 8;
  float4 a = *(const float4*)wf;
  float4 c = *(const float4*)(wf + 4);
  r[0] = bfr(a.x) | (bfr(a.y) << 16);
  r[1] = bfr(a.z) | (bfr(a.w) << 16);
  r[2] = bfr(c.x) | (bfr(c.y) << 16);
  r[3] = bfr(c.z) | (bfr(c.w) << 16);
}

__device__ __forceinline__ float dotchunk(const uint32* r, const float* xc, int lane) {
  const float* x = xc + lane * 8;
  float4 x0 = *(const float4*)x, x1 = *(const float4*)(x + 4);
  return blo(r[0]) * x0.x + bhi(r[0]) * x0.y + blo(r[1]) * x0.z + bhi(r[1]) * x0.w +
         blo(r[2]) * x1.x + bhi(r[2]) * x1.y + blo(r[3]) * x1.z + bhi(r[3]) * x1.w;
}

__device__ __forceinline__ float sigm(float x) { return 1.f / (1.f + expf(-x)); }
__device__ __forceinline__ float lrelu(float x) { return x >= 0.f ? x : 0.01f * x; }

__global__ __launch_bounds__(BT, 2) void dec_cnt_kernel(Params p) {
  // sx: [0:512) emb | [512:2560) ctx | [2560:3584) o2/o1 | [4096:4352) e |
  //     [6144:7168) h1 | [7168:8192) h2
  __shared__ float sx[8192];
  __shared__ float s_red[8];
  __shared__ float s_part[72];

  const int tid = threadIdx.x;
  const int lane = tid & 63;
  const int w = tid >> 6;
  const int b = blockIdx.x;
  const int gw = b * 8 + w;          // 0..2047
  const int i0 = b * 4;
  const int j0 = b * 8;

  int* wsi = (int*)p.ws;

  float* outs = p.out;            // 128*512
  float* pres = p.out + 65536;    // 128*1024
  float* alph = p.out + 196608;   // 128*256
  float* h1f = p.out + 229376;
  float* h2f = p.out + 230400;

  // ======== Register-resident weights (once) ========
  uint32 wa[48];
  if (gw < 1024) {
#pragma unroll
    for (int c = 0; c < 7; ++c)
      ldchunk(p.Wpre, (size_t)gw * 3584 + c * 512, lane, wa + 4 * c);
    ldchunk(p.Whh1, (size_t)gw * 1024, lane, wa + 28);
    ldchunk(p.Whh1, (size_t)gw * 1024 + 512, lane, wa + 32);
    ldchunk(p.Whh1, (size_t)(gw + 1024) * 1024, lane, wa + 36);
    ldchunk(p.Whh1, (size_t)(gw + 1024) * 1024 + 512, lane, wa + 40);
    wa[44] = wa[45] = wa[46] = wa[47] = 0u;
  } else {
    const int widx = gw - 1024;
    ldchunk(p.Whh1, (size_t)(2048 + widx) * 1024, lane, wa + 0);
    ldchunk(p.Whh1, (size_t)(2048 + widx) * 1024 + 512, lane, wa + 4);
#pragma unroll
    for (int r = 0; r < 3; ++r) {
      ldchunk(p.Whh2, (size_t)(widx + r * 1024) * 1024, lane, wa + 8 + 8 * r);
      ldchunk(p.Whh2, (size_t)(widx + r * 1024) * 1024 + 512, lane, wa + 12 + 8 * r);
    }
    ldchunk(p.Wq, (size_t)widx * 1024, lane, wa + 32);
    ldchunk(p.Wq, (size_t)widx * 1024 + 512, lane, wa + 36);
    const int wr = widx & 511;  // clamp; store guarded by widx<512
    ldchunk(p.Wout, (size_t)wr * 1024, lane, wa + 40);
    ldchunk(p.Wout, (size_t)wr * 1024 + 512, lane, wa + 44);
  }

  uint32 wd[32];
#pragma unroll
  for (int k = 0; k < 8; ++k) {
    const int mm = w + 8 * k;
    const int mmc = mm < 60 ? mm : 0;
    const int r = mmc / 15, m = mmc % 15, g = m / 5, c = m % 5;
    ldchunk(p.Wih1, (size_t)(g * 1024 + i0 + r) * 2560 + c * 512, lane, wd + 4 * k);
  }

  uint32 we9[36];
#pragma unroll
  for (int k = 0; k < 9; ++k) {
    const int mm = w + 8 * k;
    const int r = mm / 18, m = mm % 18, g = m / 6, c = m % 6;
    ldchunk(p.Wih2, (size_t)(g * 1024 + i0 + r) * 3072 + c * 512, lane, we9 + 4 * k);
  }

  uint32 wenc[4] = {0u, 0u, 0u, 0u};
  float4 pk4 = {0.f, 0.f, 0.f, 0.f}, va4 = {0.f, 0.f, 0.f, 0.f};
  if (tid < 256) {
    const float* er = p.enc + (size_t)tid * 2048 + j0;
    float4 a = *(const float4*)er, c = *(const float4*)(er + 4);
    wenc[0] = bfr(a.x) | (bfr(a.y) << 16);
    wenc[1] = bfr(a.z) | (bfr(a.w) << 16);
    wenc[2] = bfr(c.x) | (bfr(c.y) << 16);
    wenc[3] = bfr(c.z) | (bfr(c.w) << 16);
    pk4 = *(const float4*)(p.pk + (size_t)b * 1024 + 4 * tid);
    va4 = *(const float4*)(p.vatt + 4 * tid);
  }

  // ======== init recurrent state: block owns rows i0..i0+3 ========
  if (tid < 4) {
    ast(p.ws + H1FO + i0 + tid, p.h1_in[i0 + tid]);
    ast(p.ws + H2FO + i0 + tid, p.h2_in[i0 + tid]);
  }
  VDRAIN();  // wave 0 drains its stores; tid 0 (wave 0) then publishes
  if (tid == 0) { cadd(wsi, CH1, b); cadd(wsi, CH2, b); }

  for (int t = 0; t <= NSTEP; ++t) {
    if (t < NSTEP) {
      // ======== A1: q + gh1 + gh2 (reads h1/h2 of step t-1) ========
      if (tid == 0) { cpoll(wsi, CH1, 32 * (t + 1)); cpoll(wsi, CH2, 32 * (t + 1)); }
      __syncthreads();
      if (tid < 256 || b >= 128) {  // blocks<128 need only h1
        const float* hsrc = (tid < 256) ? (p.ws + H1FO + 4 * tid)
                                        : (p.ws + H2FO + 4 * (tid - 256));
        float4 hv = cld16(hsrc);
        *(float4*)&sx[6144 + 4 * tid] = hv;
      }
      __syncthreads();
      if (b >= 128) {
        const int widx = gw - 1024;
        // q first (critical path head)
        float sq = dotchunk(wa + 32, sx + 7168, lane) + dotchunk(wa + 36, sx + 7680, lane);
        sq = wsum(sq);
        if (lane == 0) ast(p.ws + QF + widx, sq);
        VDRAIN();
        __syncthreads();
        if (tid == 0) cadd(wsi, CQ, b);
        float s = dotchunk(wa + 0, sx + 6144, lane) + dotchunk(wa + 4, sx + 6656, lane);
        s = wsum(s);
        if (lane == 0) ast(p.ws + GH1F + widx * 4 + 2, s + p.bhh1[2048 + widx]);
#pragma unroll
        for (int r = 0; r < 3; ++r) {
          float t2 = dotchunk(wa + 8 + 8 * r, sx + 7168, lane) +
                     dotchunk(wa + 12 + 8 * r, sx + 7680, lane);
          t2 = wsum(t2);
          if (lane == 0) ast(p.ws + GH2F + widx * 4 + r, t2 + p.bhh2[widx + 1024 * r]);
        }
        VDRAIN();
        __syncthreads();
        if (tid == 0) cadd(wsi, CGH, b);
      } else {
        float s1 = dotchunk(wa + 28, sx + 6144, lane) + dotchunk(wa + 32, sx + 6656, lane);
        s1 = wsum(s1);
        if (lane == 0) ast(p.ws + GH1F + gw * 4 + 0, s1 + p.bhh1[gw]);
        float s2 = dotchunk(wa + 36, sx + 6144, lane) + dotchunk(wa + 40, sx + 6656, lane);
        s2 = wsum(s2);
        if (lane == 0) ast(p.ws + GH1F + gw * 4 + 1, s2 + p.bhh1[1024 + gw]);
        VDRAIN();
        __syncthreads();
        if (tid == 0) cadd(wsi, CGH, b);
      }

      // ======== C1: e[b] = v . tanh(pk + q) ========
      if (tid == 0) cpoll(wsi, CQ, 16 * (t + 1));
      __syncthreads();
      if (tid < 256) {
        float4 qv = cld16(p.ws + QF + 4 * tid);
        float acc = va4.x * tanhf(pk4.x + qv.x) + va4.y * tanhf(pk4.y + qv.y) +
                    va4.z * tanhf(pk4.z + qv.z) + va4.w * tanhf(pk4.w + qv.w);
        acc = wsum(acc);
        if (lane == 0) s_red[w] = acc;
      }
      __syncthreads();
      if (tid == 0) {
        float e = s_red[0] + s_red[1] + s_red[2] + s_red[3];
        ast(p.ws + EF + b, e);
        VDRAIN();
        cadd(wsi, CE, b);
      }
    }

    // ======== A2: epilogue(t-1) pre + out (hidden in CE rendezvous wait) ====
    // Reuses emb(t-1) @ sx[0:512) and ctx(t-1) @ sx[512:2560) staged by D(t-1).
    if (t > 0) {
      if (t == NSTEP) {
        if (tid == 0) cpoll(wsi, CH2, 32 * (t + 1));
      }
      __syncthreads();
      if (tid < 256) {
        float4 v = cld16(p.ws + O2F + 4 * tid);
        *(float4*)&sx[2560 + 4 * tid] = v;
      }
      __syncthreads();
      if (gw < 1024) {
        float s = 0.f;
#pragma unroll
        for (int c = 0; c < 7; ++c) {
          const float* xp = (c == 0) ? sx
                          : (c <= 2) ? (sx + 2560 + (c - 1) * 512)
                                     : (sx + 512 + (c - 3) * 512);
          s += dotchunk(wa + 4 * c, xp, lane);
        }
        s = wsum(s);
        if (lane == 0) pres[(size_t)(t - 1) * 1024 + gw] = lrelu(s + p.bpre[gw]);
      } else if (gw - 1024 < 512) {
        const int widx = gw - 1024;
        float so = dotchunk(wa + 40, sx + 2560, lane) + dotchunk(wa + 44, sx + 3072, lane);
        so = wsum(so);
        if (lane == 0) outs[(size_t)(t - 1) * 512 + widx] = so + p.bout[widx];
      }
    }
    if (t == NSTEP) break;

    // ======== C2: softmax over e + ctx columns ========
    {
      if (tid == 0) cpoll(wsi, CE, 32 * (t + 1));
      __syncthreads();
      if (tid < 64) {
        float4 ev = cld16(p.ws + EF + 4 * tid);
        *(float4*)&sx[4096 + 4 * tid] = ev;
      }
      __syncthreads();
      float e_i = 0.f, pe = 0.f;
      if (tid < 256) {
        e_i = sx[4096 + tid];
        float mw = e_i;
#pragma unroll
        for (int o = 32; o; o >>= 1) mw = fmaxf(mw, __shfl_xor(mw, o, 64));
        if (lane == 0) s_red[w] = mw;
      }
      __syncthreads();
      float m = fmaxf(fmaxf(s_red[0], s_red[1]), fmaxf(s_red[2], s_red[3]));
      __syncthreads();
      if (tid < 256) {
        pe = expf(e_i - m);
        float zw = wsum(pe);
        if (lane == 0) s_red[w] = zw;
      }
      __syncthreads();
      float Z = s_red[0] + s_red[1] + s_red[2] + s_red[3];
      if (tid < 256) {
        float alpha = pe / Z;
        if (b == 0) alph[(size_t)t * 256 + tid] = alpha;
        float c[8];
        c[0] = alpha * blo(wenc[0]); c[1] = alpha * bhi(wenc[0]);
        c[2] = alpha * blo(wenc[1]); c[3] = alpha * bhi(wenc[1]);
        c[4] = alpha * blo(wenc[2]); c[5] = alpha * bhi(wenc[2]);
        c[6] = alpha * blo(wenc[3]); c[7] = alpha * bhi(wenc[3]);
#pragma unroll
        for (int o = 32; o; o >>= 1) {
#pragma unroll
          for (int j = 0; j < 8; ++j) c[j] += __shfl_xor(c[j], o, 64);
        }
        if (lane == 0) {
#pragma unroll
          for (int j = 0; j < 8; ++j) s_part[w * 8 + j] = c[j];
        }
      }
      __syncthreads();
      if (tid < 8) {
        float cj = s_part[tid] + s_part[8 + tid] + s_part[16 + tid] + s_part[24 + tid];
        ast(p.ws + CTXF + j0 + tid, cj);
      }
      VDRAIN();  // wave 0 drains; tid0 publishes
      if (tid == 0) cadd(wsi, CCTX, b);
    }

    // ======== D: GRU1; x=[emb(t)|ctx(t)] @ sx[0:2560) ========
    {
      if (tid == 0) { cpoll(wsi, CCTX, 32 * (t + 1)); cpoll(wsi, CGH, 32 * (t + 1)); }
      __syncthreads();
      const float* embc = p.embeds + (size_t)p.inputs[t] * 512;
      sx[tid] = embc[tid];
      {
        float4 cv = cld16(p.ws + CTXF + 4 * tid);
        *(float4*)&sx[512 + 4 * tid] = cv;
      }
      float4 g1 = {0.f, 0.f, 0.f, 0.f};
      float h1old = 0.f;
      if (tid < 4) {
        g1 = cld16(p.ws + GH1F + (i0 + tid) * 4);
        h1old = ald(p.ws + H1FO + i0 + tid);
      }
      __syncthreads();
#pragma unroll
      for (int k = 0; k < 8; ++k) {
        const int mm = w + 8 * k;
        if (mm < 60) {  // wave-uniform
          const int c = (mm % 15) % 5;
          float s = dotchunk(wd + 4 * k, sx + c * 512, lane);
          s = wsum(s);
          if (lane == 0) s_part[mm] = s;
        }
      }
      __syncthreads();
      if (tid < 4) {
        const int i = i0 + tid;
        const float* sp = s_part + tid * 15;
        float sr = sp[0] + sp[1] + sp[2] + sp[3] + sp[4];
        float sz = sp[5] + sp[6] + sp[7] + sp[8] + sp[9];
        float sn = sp[10] + sp[11] + sp[12] + sp[13] + sp[14];
        float r = sigm(sr + p.bih1[i] + g1.x);
        float z = sigm(sz + p.bih1[1024 + i] + g1.y);
        float n = tanhf(sn + p.bih1[2048 + i] + r * g1.z);
        float h = (1.f - z) * n + z * h1old;
        ast(p.ws + H1FO + i, h);
        ast(p.ws + O1F + i, lrelu(h));
      }
      VDRAIN();
      if (tid == 0) cadd(wsi, CH1, b);
    }

    // ======== E: GRU2; x = [o1 @ sx[2560:3584) | ctx @ sx[512:2560)] ========
    {
      if (tid == 0) cpoll(wsi, CH1, 32 * (t + 2));
      __syncthreads();
      if (tid < 256) {
        float4 ov = cld16(p.ws + O1F + 4 * tid);
        *(float4*)&sx[2560 + 4 * tid] = ov;
      }
      float4 g2 = {0.f, 0.f, 0.f, 0.f};
      float h2old = 0.f;
      if (tid < 4) {
        g2 = cld16(p.ws + GH2F + (i0 + tid) * 4);
        h2old = ald(p.ws + H2FO + i0 + tid);
      }
      __syncthreads();
#pragma unroll
      for (int k = 0; k < 9; ++k) {
        const int mm = w + 8 * k;  // < 72 always
        const int c = (mm % 18) % 6;
        const float* xp = (c < 2) ? (sx + 2560 + c * 512) : (sx + 512 + (c - 2) * 512);
        float s = dotchunk(we9 + 4 * k, xp, lane);
        s = wsum(s);
        if (lane == 0) s_part[mm] = s;
      }
      __syncthreads();
      if (tid < 4) {
        const int i = i0 + tid;
        const float* sp = s_part + tid * 18;
        float sr = sp[0] + sp[1] + sp[2] + sp[3] + sp[4] + sp[5];
        float sz = sp[6] + sp[7] + sp[8] + sp[9] + sp[10] + sp[11];
        float sn = sp[12] + sp[13] + sp[14] + sp[15] + sp[16] + sp[17];
        float r = sigm(sr + p.bih2[i] + g2.x);
        float z = sigm(sz + p.bih2[1024 + i] + g2.y);
        float n = tanhf(sn + p.bih2[2048 + i] + r * g2.z);
        float h = (1.f - z) * n + z * h2old;
        ast(p.ws + H2FO + i, h);
        ast(p.ws + O2F + i, lrelu(h));
      }
      VDRAIN();
      if (tid == 0) cadd(wsi, CH2, b);
    }
  }

  // ======== Final state outputs: block writes its own rows ========
  if (tid < 4) {
    h1f[i0 + tid] = ald(p.ws + H1FO + i0 + tid);
    h2f[i0 + tid] = ald(p.ws + H2FO + i0 + tid);
  }
}

extern "C" void kernel_launch(void* const* d_in, const int* in_sizes, int n_in,
                              void* d_out, int out_size, void* d_ws, size_t ws_size,
                              hipStream_t stream) {
  (void)hipMemsetAsync(d_ws, 0, 4096, stream);  // zero arrival counters

  Params p;
  p.inputs = (const int*)d_in[0];
  p.h1_in = (const float*)d_in[1];
  p.h2_in = (const float*)d_in[2];
  p.pk = (const float*)d_in[3];
  p.enc = (const float*)d_in[4];
  p.embeds = (const float*)d_in[5];
  p.Wq = (const float*)d_in[6];
  p.vatt = (const float*)d_in[7];
  p.Wih1 = (const float*)d_in[8];
  p.Whh1 = (const float*)d_in[9];
  p.bih1 = (const float*)d_in[10];
  p.bhh1 = (const float*)d_in[11];
  p.Wih2 = (const float*)d_in[12];
  p.Whh2 = (const float*)d_in[13];
  p.bih2 = (const float*)d_in[14];
  p.bhh2 = (const float*)d_in[15];
  p.Wpre = (const float*)d_in[16];
  p.bpre = (const float*)d_in[17];
  p.Wout = (const float*)d_in[18];
  p.bout = (const float*)d_in[19];
  p.out = (float*)d_out;
  p.ws = (float*)d_ws;

  void* args[] = {&p};
  hipError_t err = hipLaunchCooperativeKernel((const void*)dec_cnt_kernel,
                                              dim3(GBLK), dim3(BT), args, 0, stream);
  if (err != hipSuccess) {
    // Fallback: plain launch. 256 blocks at 1 block/CU are trivially co-resident,
    // so the dataflow polling remains safe.
    dec_cnt_kernel<<<dim3(GBLK), dim3(BT), 0, stream>>>(p);
  }
}